// Round 1
// 283.023 us; speedup vs baseline: 1.1123x; 1.1123x over previous
//
#include <hip/hip_runtime.h>

#define N_NODES 100000
#define N_EDGES 1600000
// DIN=128, DH=128, DOUT=64
#define BUCKET_SHIFT 9
#define NB 196                 // ceil(100000/512) super-buckets of 512 nodes
#define BIN_BLOCKS 782         // ceil(1600000/2048)
#define GEMM_BLOCKS 1563       // ceil(100000/64)
#define BCAP 10240             // per-bucket ebuf capacity (mean 8163, +23 sigma)

typedef short bf16x8 __attribute__((ext_vector_type(8)));
typedef float f32x4 __attribute__((ext_vector_type(4)));
typedef float f32x8 __attribute__((ext_vector_type(8)));

// bf16 helpers (RNE)
__device__ __forceinline__ unsigned short f2bf(float f) {
    unsigned int u = __float_as_uint(f);
    unsigned int r = (u + 0x7FFFu + ((u >> 16) & 1u)) >> 16;
    return (unsigned short)r;
}
__device__ __forceinline__ float bf2f(unsigned short b) {
    return __uint_as_float(((unsigned int)b) << 16);
}

// ---------------- weight transpose+cvt (+ zero bcur in spare threads) ----------------
__global__ __launch_bounds__(256) void k_tw(const float* __restrict__ W1, const float* __restrict__ W2,
                                            unsigned short* __restrict__ w1t, unsigned short* __restrict__ w2t,
                                            int* __restrict__ bcur) {
    int t = blockIdx.x * 256 + threadIdx.x;
    if (t < 16384) {
        int k = t >> 7, c = t & 127;
        w1t[c * 128 + k] = f2bf(W1[t]);
    } else if (t < 24576) {
        int i = t - 16384;
        int k = i >> 6, c = i & 63;
        w2t[c * 128 + k] = f2bf(W2[i]);
    } else if (t - 24576 < NB) {
        bcur[t - 24576] = 0;
    }
}

// ---------------- bin edges into fixed-capacity bucket slabs ----------------
__global__ __launch_bounds__(256) void k_bin(const int* __restrict__ src, const int* __restrict__ dst,
                                             int* __restrict__ bcur, int* __restrict__ ebuf) {
    __shared__ int hist[NB];
    __shared__ int lbase[NB];
    int t = threadIdx.x;
    int e0 = blockIdx.x * 2048 + t;
    int s[8], d[8];
#pragma unroll
    for (int j = 0; j < 8; ++j) {
        int e = e0 + j * 256;
        bool ok = e < N_EDGES;
        s[j] = ok ? src[e] : -1;
        d[j] = ok ? dst[e] : 0;
    }
    if (t < NB) hist[t] = 0;
    __syncthreads();
#pragma unroll
    for (int j = 0; j < 8; ++j)
        if (s[j] >= 0) atomicAdd(&hist[d[j] >> BUCKET_SHIFT], 1);
    __syncthreads();
    if (t < NB && hist[t] > 0) lbase[t] = atomicAdd(&bcur[t], hist[t]);
    __syncthreads();
    if (t < NB) hist[t] = 0;
    __syncthreads();
#pragma unroll
    for (int j = 0; j < 8; ++j) {
        if (s[j] >= 0) {
            int b = d[j] >> BUCKET_SHIFT;
            int r = lbase[b] + atomicAdd(&hist[b], 1);
            if (r < BCAP) ebuf[b * BCAP + r] = ((d[j] & 511) << 17) | s[j];
        }
    }
}

// ---------------- per-bucket: counts -> rowptr + dinv + CSR fill (one kernel) ----------------
__global__ __launch_bounds__(256) void k_bfill3(const int* __restrict__ ebuf, const int* __restrict__ bcur,
                                                int* __restrict__ rowptr, float* __restrict__ dinv,
                                                int* __restrict__ csr) {
    __shared__ int sc[256];
    __shared__ int cnt[512];
    __shared__ int cur[512];
    int b = blockIdx.x, t = threadIdx.x;
    int node0 = b << BUCKET_SHIFT;
    // bucket base: block-local exclusive scan over the 196 bucket counts
    int v = (t < NB) ? bcur[t] : 0;
    sc[t] = v;
    cnt[t] = 0;
    cnt[t + 256] = 0;
    __syncthreads();
    for (int off = 1; off < 256; off <<= 1) {
        int u = (t >= off) ? sc[t - off] : 0;
        __syncthreads();
        sc[t] += u;
        __syncthreads();
    }
    int cb = bcur[b];
    int s0 = sc[b] - cb;                 // exclusive bucket base (read before sc reuse; barrier below)
    int ctot = cb > BCAP ? BCAP : cb;
    const int* eb = ebuf + b * BCAP;
    // per-node counts from slab
    for (int i = t; i < ctot; i += 256) atomicAdd(&cnt[eb[i] >> 17], 1);
    __syncthreads();                     // also orders sc reuse after all s0 reads
    // scan 512 counts (thread t owns elements 2t, 2t+1)
    int c0 = cnt[2 * t], c1 = cnt[2 * t + 1];
    int ps = c0 + c1;
    sc[t] = ps;
    __syncthreads();
    for (int off = 1; off < 256; off <<= 1) {
        int u = (t >= off) ? sc[t - off] : 0;
        __syncthreads();
        sc[t] += u;
        __syncthreads();
    }
    int e0x = sc[t] - ps;
    int p0 = s0 + e0x, p1 = s0 + e0x + c0;
    int n0 = node0 + 2 * t, n1 = n0 + 1;
    if (n0 < N_NODES) { rowptr[n0] = p0; dinv[n0] = rsqrtf(1.0f + (float)c0); }
    if (n1 < N_NODES) { rowptr[n1] = p1; dinv[n1] = rsqrtf(1.0f + (float)c1); }
    if (b == NB - 1 && t == 0) rowptr[N_NODES] = N_EDGES;
    cur[2 * t] = p0;
    cur[2 * t + 1] = p1;
    __syncthreads();
    // fill csr
    for (int i = t; i < ctot; i += 256) {
        int e = eb[i];
        int p = atomicAdd(&cur[e >> 17], 1);
        csr[p] = e & 0x1FFFF;
    }
}

// ---------------- GEMM1 (MFMA bf16): hsb = bf16((x @ W1) * dinv[row]) ----------------
__global__ __launch_bounds__(256) void k_gemm1(const float* __restrict__ x, const unsigned short* __restrict__ w1t,
                                               const float* __restrict__ dinv, unsigned short* __restrict__ hsb) {
    __shared__ unsigned short Xl[64 * 136];
    __shared__ unsigned short Wl[128 * 136];
    int t = threadIdx.x;
    int row0 = blockIdx.x * 64;
    for (int i = t; i < 64 * 32; i += 256) {
        int r = i >> 5, c4 = i & 31;
        int row = row0 + r;
        float4 v = (row < N_NODES) ? ((const float4*)x)[(long long)row * 32 + c4]
                                   : make_float4(0.f, 0.f, 0.f, 0.f);
        ushort4 o;
        o.x = f2bf(v.x); o.y = f2bf(v.y); o.z = f2bf(v.z); o.w = f2bf(v.w);
        *(ushort4*)&Xl[r * 136 + c4 * 4] = o;
    }
    for (int i = t; i < 128 * 16; i += 256) {
        int r = i >> 4, c8 = i & 15;
        *(bf16x8*)&Wl[r * 136 + c8 * 8] = *(const bf16x8*)&w1t[r * 128 + c8 * 8];
    }
    __syncthreads();
    int w = t >> 6, lane = t & 63;
    int nn = lane & 15, quad = lane >> 4;
    bf16x8 a[4];
#pragma unroll
    for (int kt = 0; kt < 4; ++kt)
        a[kt] = *(const bf16x8*)&Xl[(w * 16 + nn) * 136 + kt * 32 + quad * 8];
    f32x4 acc[8];
#pragma unroll
    for (int ct = 0; ct < 8; ++ct) {
        acc[ct] = (f32x4){0.f, 0.f, 0.f, 0.f};
#pragma unroll
        for (int kt = 0; kt < 4; ++kt) {
            bf16x8 b = *(const bf16x8*)&Wl[(ct * 16 + nn) * 136 + kt * 32 + quad * 8];
            acc[ct] = __builtin_amdgcn_mfma_f32_16x16x32_bf16(a[kt], b, acc[ct], 0, 0, 0);
        }
    }
#pragma unroll
    for (int r = 0; r < 4; ++r) {
        int row = row0 + w * 16 + quad * 4 + r;
        float dv = (row < N_NODES) ? dinv[row] : 0.f;
#pragma unroll
        for (int ct = 0; ct < 8; ++ct)
            Xl[(w * 16 + quad * 4 + r) * 136 + ct * 16 + nn] = f2bf(acc[ct][r] * dv);
    }
#pragma unroll
    for (int j = 0; j < 8; ++j) {
        int c = lane + j * 64;
        int r = c >> 5, c4 = c & 31;
        int row = row0 + w * 16 + r;
        if (row < N_NODES)
            ((ushort4*)(hsb + (long long)row * 128))[c4] = *(const ushort4*)&Xl[(w * 16 + r) * 136 + c4 * 4];
    }
}

// ---------------- aggregate layer 1: 4 rows per gather instruction (16-lane groups, 16B loads) ----------------
__global__ __launch_bounds__(256) void k_agg1(const unsigned short* __restrict__ hsb, const int* __restrict__ rowptr,
                                              const int* __restrict__ csr, const float* __restrict__ dinv,
                                              const float* __restrict__ b1, unsigned short* __restrict__ h) {
    int n = (blockIdx.x * 256 + threadIdx.x) >> 6;
    int lane = threadIdx.x & 63;
    if (n >= N_NODES) return;
    int q = lane >> 4, li = lane & 15;           // 4 groups of 16 lanes; group covers full 256B row
    float a[8];
    {   // self-loop seed on group 0 only (all groups hit the same cache lines)
        bf16x8 sv = *(const bf16x8*)(hsb + (long long)n * 128 + li * 8);
        float z = (q == 0) ? 1.f : 0.f;
#pragma unroll
        for (int j = 0; j < 8; ++j) a[j] = z * bf2f((unsigned short)sv[j]);
    }
    int k = rowptr[n], end = rowptr[n + 1];
    // tier A: 16 edges / iter, 4 independent gathers in flight
    for (; k + 15 < end; k += 16) {
        int ia = csr[k + q];
        int ib = csr[k + 4 + q];
        int ic = csr[k + 8 + q];
        int id = csr[k + 12 + q];
        bf16x8 va = *(const bf16x8*)(hsb + (long long)ia * 128 + li * 8);
        bf16x8 vb = *(const bf16x8*)(hsb + (long long)ib * 128 + li * 8);
        bf16x8 vc = *(const bf16x8*)(hsb + (long long)ic * 128 + li * 8);
        bf16x8 vd = *(const bf16x8*)(hsb + (long long)id * 128 + li * 8);
#pragma unroll
        for (int j = 0; j < 8; ++j)
            a[j] += (bf2f((unsigned short)va[j]) + bf2f((unsigned short)vb[j])) +
                    (bf2f((unsigned short)vc[j]) + bf2f((unsigned short)vd[j]));
    }
    // tier B: 8 edges
    if (k + 7 < end) {
        int ia = csr[k + q];
        int ib = csr[k + 4 + q];
        bf16x8 va = *(const bf16x8*)(hsb + (long long)ia * 128 + li * 8);
        bf16x8 vb = *(const bf16x8*)(hsb + (long long)ib * 128 + li * 8);
#pragma unroll
        for (int j = 0; j < 8; ++j)
            a[j] += bf2f((unsigned short)va[j]) + bf2f((unsigned short)vb[j]);
        k += 8;
    }
    // tier C: 4 edges
    if (k + 3 < end) {
        int ia = csr[k + q];
        bf16x8 va = *(const bf16x8*)(hsb + (long long)ia * 128 + li * 8);
#pragma unroll
        for (int j = 0; j < 8; ++j) a[j] += bf2f((unsigned short)va[j]);
        k += 4;
    }
    // tier D: remainder (<4), one edge per active group
    {
        int kk = k + q;
        if (kk < end) {
            int idx = csr[kk];
            bf16x8 v = *(const bf16x8*)(hsb + (long long)idx * 128 + li * 8);
#pragma unroll
            for (int j = 0; j < 8; ++j) a[j] += bf2f((unsigned short)v[j]);
        }
    }
#pragma unroll
    for (int j = 0; j < 8; ++j) {
        a[j] += __shfl_xor(a[j], 16);
        a[j] += __shfl_xor(a[j], 32);
    }
    if (q == 0) {
        float dv = dinv[n];
        f32x8 bb = *(const f32x8*)(b1 + li * 8);
        bf16x8 o;
#pragma unroll
        for (int j = 0; j < 8; ++j)
            o[j] = (short)f2bf(fmaxf(fmaf(dv, a[j], bb[j]), 0.f));
        *(bf16x8*)(h + (long long)n * 128 + li * 8) = o;
    }
}

// ---------------- GEMM2 (MFMA bf16): gsb = bf16((h @ W2) * dinv[row]) ----------------
__global__ __launch_bounds__(256) void k_gemm2(const unsigned short* __restrict__ h, const unsigned short* __restrict__ w2t,
                                               const float* __restrict__ dinv, unsigned short* __restrict__ gsb) {
    __shared__ unsigned short Hl[64 * 136];
    __shared__ unsigned short Wl[64 * 136];
    int t = threadIdx.x;
    int row0 = blockIdx.x * 64;
    for (int i = t; i < 64 * 16; i += 256) {
        int r = i >> 4, c8 = i & 15;
        int row = row0 + r;
        bf16x8 v = (row < N_NODES) ? *(const bf16x8*)&h[(long long)row * 128 + c8 * 8]
                                   : (bf16x8){0, 0, 0, 0, 0, 0, 0, 0};
        *(bf16x8*)&Hl[r * 136 + c8 * 8] = v;
        *(bf16x8*)&Wl[r * 136 + c8 * 8] = *(const bf16x8*)&w2t[r * 128 + c8 * 8];
    }
    __syncthreads();
    int w = t >> 6, lane = t & 63;
    int nn = lane & 15, quad = lane >> 4;
    bf16x8 a[4];
#pragma unroll
    for (int kt = 0; kt < 4; ++kt)
        a[kt] = *(const bf16x8*)&Hl[(w * 16 + nn) * 136 + kt * 32 + quad * 8];
    f32x4 acc[4];
#pragma unroll
    for (int ct = 0; ct < 4; ++ct) {
        acc[ct] = (f32x4){0.f, 0.f, 0.f, 0.f};
#pragma unroll
        for (int kt = 0; kt < 4; ++kt) {
            bf16x8 b = *(const bf16x8*)&Wl[(ct * 16 + nn) * 136 + kt * 32 + quad * 8];
            acc[ct] = __builtin_amdgcn_mfma_f32_16x16x32_bf16(a[kt], b, acc[ct], 0, 0, 0);
        }
    }
#pragma unroll
    for (int r = 0; r < 4; ++r) {
        int row = row0 + w * 16 + quad * 4 + r;
        float dv = (row < N_NODES) ? dinv[row] : 0.f;
#pragma unroll
        for (int ct = 0; ct < 4; ++ct)
            Hl[(w * 16 + quad * 4 + r) * 136 + ct * 16 + nn] = f2bf(acc[ct][r] * dv);
    }
#pragma unroll
    for (int j = 0; j < 4; ++j) {
        int c = lane + j * 64;
        int r = c >> 4, c4 = c & 15;
        int row = row0 + w * 16 + r;
        if (row < N_NODES)
            ((ushort4*)(gsb + (long long)row * 64))[c4] = *(const ushort4*)&Hl[(w * 16 + r) * 136 + c4 * 4];
    }
}

// ---------------- aggregate layer 2: 8 rows per gather instruction (8-lane groups, 16B loads) ----------------
__global__ __launch_bounds__(256) void k_agg2(const unsigned short* __restrict__ gsb, const int* __restrict__ rowptr,
                                              const int* __restrict__ csr, const float* __restrict__ dinv,
                                              const float* __restrict__ b2, float* __restrict__ out) {
    int n = (blockIdx.x * 256 + threadIdx.x) >> 6;
    int lane = threadIdx.x & 63;
    if (n >= N_NODES) return;
    int oc = lane >> 3, li = lane & 7;           // 8 groups of 8 lanes; group covers full 128B row
    float a[8];
    {   // self-loop seed on group 0 only
        bf16x8 sv = *(const bf16x8*)(gsb + (long long)n * 64 + li * 8);
        float z = (oc == 0) ? 1.f : 0.f;
#pragma unroll
        for (int j = 0; j < 8; ++j) a[j] = z * bf2f((unsigned short)sv[j]);
    }
    int k = rowptr[n], end = rowptr[n + 1];
    // tier A: 16 edges / iter, 2 gathers x 8 rows each
    for (; k + 15 < end; k += 16) {
        int ia = csr[k + oc];
        int ib = csr[k + 8 + oc];
        bf16x8 va = *(const bf16x8*)(gsb + (long long)ia * 64 + li * 8);
        bf16x8 vb = *(const bf16x8*)(gsb + (long long)ib * 64 + li * 8);
#pragma unroll
        for (int j = 0; j < 8; ++j)
            a[j] += bf2f((unsigned short)va[j]) + bf2f((unsigned short)vb[j]);
    }
    // tier B: 8 edges
    if (k + 7 < end) {
        int ia = csr[k + oc];
        bf16x8 va = *(const bf16x8*)(gsb + (long long)ia * 64 + li * 8);
#pragma unroll
        for (int j = 0; j < 8; ++j) a[j] += bf2f((unsigned short)va[j]);
        k += 8;
    }
    // tier C: remainder (<8), one edge per active group
    {
        int kk = k + oc;
        if (kk < end) {
            int idx = csr[kk];
            bf16x8 v = *(const bf16x8*)(gsb + (long long)idx * 64 + li * 8);
#pragma unroll
            for (int j = 0; j < 8; ++j) a[j] += bf2f((unsigned short)v[j]);
        }
    }
#pragma unroll
    for (int j = 0; j < 8; ++j) {
        a[j] += __shfl_xor(a[j], 8);
        a[j] += __shfl_xor(a[j], 16);
        a[j] += __shfl_xor(a[j], 32);
    }
    if (oc == 0) {
        float dv = dinv[n];
        f32x8 bb = *(const f32x8*)(b2 + li * 8);
        f32x8 o;
#pragma unroll
        for (int j = 0; j < 8; ++j)
            o[j] = fmaf(dv, a[j], bb[j]);
        *(f32x8*)(out + (long long)n * 64 + li * 8) = o;
    }
}

extern "C" void kernel_launch(void* const* d_in, const int* in_sizes, int n_in,
                              void* d_out, int out_size, void* d_ws, size_t ws_size,
                              hipStream_t stream) {
    const float* x  = (const float*)d_in[0];
    const float* W1 = (const float*)d_in[1];
    const float* b1 = (const float*)d_in[2];
    const float* W2 = (const float*)d_in[3];
    const float* b2 = (const float*)d_in[4];
    const int*   ei = (const int*)d_in[5];
    const int* src = ei;
    const int* dst = ei + N_EDGES;
    float* out = (float*)d_out;

    char* ws = (char*)d_ws;
    int*   csr    = (int*)(ws + 0);             // 6.4 MB
    int*   rowptr = (int*)(ws + 6800000);       // 400 KB + 4
    float* dinv   = (float*)(ws + 7200256);     // 400 KB
    int*   bcur   = (int*)(ws + 7604352);       // NB ints
    unsigned short* w1t = (unsigned short*)(ws + 7608448);  // 32 KB bf16 W1^T
    unsigned short* w2t = (unsigned short*)(ws + 7641216);  // 16 KB bf16 W2^T
    int*   ebuf   = (int*)(ws + 8388608);       // 196*10240*4 = 8.03 MB (dead before gemm1)
    unsigned short* hsb = (unsigned short*)(ws + 8388608);  // 25.6 MB bf16 (aliases ebuf)
    unsigned short* h   = (unsigned short*)(ws + 59588608); // 25.6 MB bf16
    unsigned short* gsb = hsb;                   // hsb dead after k_agg1; 12.8 MB bf16

    k_tw<<<97, 256, 0, stream>>>(W1, W2, w1t, w2t, bcur);
    k_bin<<<BIN_BLOCKS, 256, 0, stream>>>(src, dst, bcur, ebuf);
    k_bfill3<<<NB, 256, 0, stream>>>(ebuf, bcur, rowptr, dinv, csr);

    k_gemm1<<<GEMM_BLOCKS, 256, 0, stream>>>(x, w1t, dinv, hsb);
    k_agg1<<<(N_NODES * 64) / 256, 256, 0, stream>>>(hsb, rowptr, csr, dinv, b1, h);
    k_gemm2<<<GEMM_BLOCKS, 256, 0, stream>>>(h, w2t, dinv, gsb);
    k_agg2<<<(N_NODES * 64) / 256, 256, 0, stream>>>(gsb, rowptr, csr, dinv, b2, out);
}

// Round 2
// 269.116 us; speedup vs baseline: 1.1697x; 1.0517x over previous
//
#include <hip/hip_runtime.h>

#define N_NODES 100000
#define N_EDGES 1600000
// DIN=128, DH=128, DOUT=64
#define BUCKET_SHIFT 9
#define NB 196                 // ceil(100000/512) super-buckets of 512 nodes
#define BIN_BLOCKS 782         // ceil(1600000/2048)
#define GEMM_BLOCKS 1563       // ceil(100000/64)
#define BCAP 10240             // per-bucket ebuf capacity (mean 8163, +23 sigma)
#define AGG1_BLOCKS 6250       // 100000 nodes / (256/16 groups per block)
#define AGG2_BLOCKS 3125       // 100000 nodes / (256/8 groups per block)

typedef short bf16x8 __attribute__((ext_vector_type(8)));
typedef float f32x4 __attribute__((ext_vector_type(4)));
typedef float f32x8 __attribute__((ext_vector_type(8)));

// bf16 helpers (RNE)
__device__ __forceinline__ unsigned short f2bf(float f) {
    unsigned int u = __float_as_uint(f);
    unsigned int r = (u + 0x7FFFu + ((u >> 16) & 1u)) >> 16;
    return (unsigned short)r;
}
__device__ __forceinline__ float bf2f(unsigned short b) {
    return __uint_as_float(((unsigned int)b) << 16);
}
// accumulate a 16B chunk (8 bf16) into 8 f32 accumulators: 1 VALU op per convert
__device__ __forceinline__ void acc8(float* a, uint4 v) {
    a[0] += __uint_as_float(v.x << 16);
    a[1] += __uint_as_float(v.x & 0xFFFF0000u);
    a[2] += __uint_as_float(v.y << 16);
    a[3] += __uint_as_float(v.y & 0xFFFF0000u);
    a[4] += __uint_as_float(v.z << 16);
    a[5] += __uint_as_float(v.z & 0xFFFF0000u);
    a[6] += __uint_as_float(v.w << 16);
    a[7] += __uint_as_float(v.w & 0xFFFF0000u);
}

// ---------------- weight transpose+cvt (+ zero bcur in spare threads) ----------------
__global__ __launch_bounds__(256) void k_tw(const float* __restrict__ W1, const float* __restrict__ W2,
                                            unsigned short* __restrict__ w1t, unsigned short* __restrict__ w2t,
                                            int* __restrict__ bcur) {
    int t = blockIdx.x * 256 + threadIdx.x;
    if (t < 16384) {
        int k = t >> 7, c = t & 127;
        w1t[c * 128 + k] = f2bf(W1[t]);
    } else if (t < 24576) {
        int i = t - 16384;
        int k = i >> 6, c = i & 63;
        w2t[c * 128 + k] = f2bf(W2[i]);
    } else if (t - 24576 < NB) {
        bcur[t - 24576] = 0;
    }
}

// ---------------- bin edges into fixed-capacity bucket slabs ----------------
__global__ __launch_bounds__(256) void k_bin(const int* __restrict__ src, const int* __restrict__ dst,
                                             int* __restrict__ bcur, int* __restrict__ ebuf) {
    __shared__ int hist[NB];
    __shared__ int lbase[NB];
    int t = threadIdx.x;
    int e0 = blockIdx.x * 2048 + t;
    int s[8], d[8];
#pragma unroll
    for (int j = 0; j < 8; ++j) {
        int e = e0 + j * 256;
        bool ok = e < N_EDGES;
        s[j] = ok ? src[e] : -1;
        d[j] = ok ? dst[e] : 0;
    }
    if (t < NB) hist[t] = 0;
    __syncthreads();
#pragma unroll
    for (int j = 0; j < 8; ++j)
        if (s[j] >= 0) atomicAdd(&hist[d[j] >> BUCKET_SHIFT], 1);
    __syncthreads();
    if (t < NB && hist[t] > 0) lbase[t] = atomicAdd(&bcur[t], hist[t]);
    __syncthreads();
    if (t < NB) hist[t] = 0;
    __syncthreads();
#pragma unroll
    for (int j = 0; j < 8; ++j) {
        if (s[j] >= 0) {
            int b = d[j] >> BUCKET_SHIFT;
            int r = lbase[b] + atomicAdd(&hist[b], 1);
            if (r < BCAP) ebuf[b * BCAP + r] = ((d[j] & 511) << 17) | s[j];
        }
    }
}

// ---------------- per-bucket: counts -> rowptr + dinv + CSR fill (one kernel) ----------------
__global__ __launch_bounds__(256) void k_bfill3(const int* __restrict__ ebuf, const int* __restrict__ bcur,
                                                int* __restrict__ rowptr, float* __restrict__ dinv,
                                                int* __restrict__ csr) {
    __shared__ int sc[256];
    __shared__ int cnt[512];
    __shared__ int cur[512];
    int b = blockIdx.x, t = threadIdx.x;
    int node0 = b << BUCKET_SHIFT;
    // bucket base: block-local exclusive scan over the 196 bucket counts
    int v = (t < NB) ? bcur[t] : 0;
    sc[t] = v;
    cnt[t] = 0;
    cnt[t + 256] = 0;
    __syncthreads();
    for (int off = 1; off < 256; off <<= 1) {
        int u = (t >= off) ? sc[t - off] : 0;
        __syncthreads();
        sc[t] += u;
        __syncthreads();
    }
    int cb = bcur[b];
    int s0 = sc[b] - cb;                 // exclusive bucket base (read before sc reuse; barrier below)
    int ctot = cb > BCAP ? BCAP : cb;
    const int* eb = ebuf + b * BCAP;
    // per-node counts from slab
    for (int i = t; i < ctot; i += 256) atomicAdd(&cnt[eb[i] >> 17], 1);
    __syncthreads();                     // also orders sc reuse after all s0 reads
    // scan 512 counts (thread t owns elements 2t, 2t+1)
    int c0 = cnt[2 * t], c1 = cnt[2 * t + 1];
    int ps = c0 + c1;
    sc[t] = ps;
    __syncthreads();
    for (int off = 1; off < 256; off <<= 1) {
        int u = (t >= off) ? sc[t - off] : 0;
        __syncthreads();
        sc[t] += u;
        __syncthreads();
    }
    int e0x = sc[t] - ps;
    int p0 = s0 + e0x, p1 = s0 + e0x + c0;
    int n0 = node0 + 2 * t, n1 = n0 + 1;
    if (n0 < N_NODES) { rowptr[n0] = p0; dinv[n0] = rsqrtf(1.0f + (float)c0); }
    if (n1 < N_NODES) { rowptr[n1] = p1; dinv[n1] = rsqrtf(1.0f + (float)c1); }
    if (b == NB - 1 && t == 0) rowptr[N_NODES] = N_EDGES;
    cur[2 * t] = p0;
    cur[2 * t + 1] = p1;
    __syncthreads();
    // fill csr
    for (int i = t; i < ctot; i += 256) {
        int e = eb[i];
        int p = atomicAdd(&cur[e >> 17], 1);
        csr[p] = e & 0x1FFFF;
    }
}

// ---------------- GEMM1 (MFMA bf16): hsb = bf16((x @ W1) * dinv[row]) ----------------
__global__ __launch_bounds__(256) void k_gemm1(const float* __restrict__ x, const unsigned short* __restrict__ w1t,
                                               const float* __restrict__ dinv, unsigned short* __restrict__ hsb) {
    __shared__ unsigned short Xl[64 * 136];
    __shared__ unsigned short Wl[128 * 136];
    int t = threadIdx.x;
    int row0 = blockIdx.x * 64;
    for (int i = t; i < 64 * 32; i += 256) {
        int r = i >> 5, c4 = i & 31;
        int row = row0 + r;
        float4 v = (row < N_NODES) ? ((const float4*)x)[(long long)row * 32 + c4]
                                   : make_float4(0.f, 0.f, 0.f, 0.f);
        ushort4 o;
        o.x = f2bf(v.x); o.y = f2bf(v.y); o.z = f2bf(v.z); o.w = f2bf(v.w);
        *(ushort4*)&Xl[r * 136 + c4 * 4] = o;
    }
    for (int i = t; i < 128 * 16; i += 256) {
        int r = i >> 4, c8 = i & 15;
        *(bf16x8*)&Wl[r * 136 + c8 * 8] = *(const bf16x8*)&w1t[r * 128 + c8 * 8];
    }
    __syncthreads();
    int w = t >> 6, lane = t & 63;
    int nn = lane & 15, quad = lane >> 4;
    bf16x8 a[4];
#pragma unroll
    for (int kt = 0; kt < 4; ++kt)
        a[kt] = *(const bf16x8*)&Xl[(w * 16 + nn) * 136 + kt * 32 + quad * 8];
    f32x4 acc[8];
#pragma unroll
    for (int ct = 0; ct < 8; ++ct) {
        acc[ct] = (f32x4){0.f, 0.f, 0.f, 0.f};
#pragma unroll
        for (int kt = 0; kt < 4; ++kt) {
            bf16x8 b = *(const bf16x8*)&Wl[(ct * 16 + nn) * 136 + kt * 32 + quad * 8];
            acc[ct] = __builtin_amdgcn_mfma_f32_16x16x32_bf16(a[kt], b, acc[ct], 0, 0, 0);
        }
    }
#pragma unroll
    for (int r = 0; r < 4; ++r) {
        int row = row0 + w * 16 + quad * 4 + r;
        float dv = (row < N_NODES) ? dinv[row] : 0.f;
#pragma unroll
        for (int ct = 0; ct < 8; ++ct)
            Xl[(w * 16 + quad * 4 + r) * 136 + ct * 16 + nn] = f2bf(acc[ct][r] * dv);
    }
#pragma unroll
    for (int j = 0; j < 8; ++j) {
        int c = lane + j * 64;
        int r = c >> 5, c4 = c & 31;
        int row = row0 + w * 16 + r;
        if (row < N_NODES)
            ((ushort4*)(hsb + (long long)row * 128))[c4] = *(const ushort4*)&Xl[(w * 16 + r) * 136 + c4 * 4];
    }
}

// ---------------- aggregate layer 1: one 16-lane group per node, 4 nodes/wave, 8-deep gather unroll ----------------
__global__ __launch_bounds__(256) void k_agg1(const unsigned short* __restrict__ hsb, const int* __restrict__ rowptr,
                                              const int* __restrict__ csr, const float* __restrict__ dinv,
                                              const float* __restrict__ b1, unsigned short* __restrict__ h) {
    unsigned g = (blockIdx.x * 256 + threadIdx.x) >> 4;   // group id == node id
    unsigned li = threadIdx.x & 15;                       // 16 lanes x 16B = full 256B row
    if (g >= N_NODES) return;
    unsigned co = li * 8;                                  // element offset within row
    float a[8];
    {   // self-loop seed (read exactly once per node)
        uint4 sv = *(const uint4*)(hsb + (g << 7) + co);
        a[0] = __uint_as_float(sv.x << 16);
        a[1] = __uint_as_float(sv.x & 0xFFFF0000u);
        a[2] = __uint_as_float(sv.y << 16);
        a[3] = __uint_as_float(sv.y & 0xFFFF0000u);
        a[4] = __uint_as_float(sv.z << 16);
        a[5] = __uint_as_float(sv.z & 0xFFFF0000u);
        a[6] = __uint_as_float(sv.w << 16);
        a[7] = __uint_as_float(sv.w & 0xFFFF0000u);
    }
    int k = rowptr[g], end = rowptr[g + 1];
    // main tier: 8 edges / iter, 8 independent gathers in flight per group
    for (; k + 7 < end; k += 8) {
        int i0 = csr[k + 0], i1 = csr[k + 1], i2 = csr[k + 2], i3 = csr[k + 3];
        int i4 = csr[k + 4], i5 = csr[k + 5], i6 = csr[k + 6], i7 = csr[k + 7];
        uint4 v0 = *(const uint4*)(hsb + (((unsigned)i0) << 7) + co);
        uint4 v1 = *(const uint4*)(hsb + (((unsigned)i1) << 7) + co);
        uint4 v2 = *(const uint4*)(hsb + (((unsigned)i2) << 7) + co);
        uint4 v3 = *(const uint4*)(hsb + (((unsigned)i3) << 7) + co);
        uint4 v4 = *(const uint4*)(hsb + (((unsigned)i4) << 7) + co);
        uint4 v5 = *(const uint4*)(hsb + (((unsigned)i5) << 7) + co);
        uint4 v6 = *(const uint4*)(hsb + (((unsigned)i6) << 7) + co);
        uint4 v7 = *(const uint4*)(hsb + (((unsigned)i7) << 7) + co);
        acc8(a, v0); acc8(a, v1); acc8(a, v2); acc8(a, v3);
        acc8(a, v4); acc8(a, v5); acc8(a, v6); acc8(a, v7);
    }
    // 4-edge tier
    if (k + 3 < end) {
        int i0 = csr[k + 0], i1 = csr[k + 1], i2 = csr[k + 2], i3 = csr[k + 3];
        uint4 v0 = *(const uint4*)(hsb + (((unsigned)i0) << 7) + co);
        uint4 v1 = *(const uint4*)(hsb + (((unsigned)i1) << 7) + co);
        uint4 v2 = *(const uint4*)(hsb + (((unsigned)i2) << 7) + co);
        uint4 v3 = *(const uint4*)(hsb + (((unsigned)i3) << 7) + co);
        acc8(a, v0); acc8(a, v1); acc8(a, v2); acc8(a, v3);
        k += 4;
    }
    // remainder (<4)
    for (; k < end; ++k) {
        uint4 v = *(const uint4*)(hsb + (((unsigned)csr[k]) << 7) + co);
        acc8(a, v);
    }
    // epilogue: no shuffles — group owns the whole row
    float dv = dinv[g];
    f32x8 bb = *(const f32x8*)(b1 + li * 8);
    bf16x8 o;
#pragma unroll
    for (int j = 0; j < 8; ++j)
        o[j] = (short)f2bf(fmaxf(fmaf(dv, a[j], bb[j]), 0.f));
    *(bf16x8*)(h + (g << 7) + co) = o;
}

// ---------------- GEMM2 (MFMA bf16): gsb = bf16((h @ W2) * dinv[row]) ----------------
__global__ __launch_bounds__(256) void k_gemm2(const unsigned short* __restrict__ h, const unsigned short* __restrict__ w2t,
                                               const float* __restrict__ dinv, unsigned short* __restrict__ gsb) {
    __shared__ unsigned short Hl[64 * 136];
    __shared__ unsigned short Wl[64 * 136];
    int t = threadIdx.x;
    int row0 = blockIdx.x * 64;
    for (int i = t; i < 64 * 16; i += 256) {
        int r = i >> 4, c8 = i & 15;
        int row = row0 + r;
        bf16x8 v = (row < N_NODES) ? *(const bf16x8*)&h[(long long)row * 128 + c8 * 8]
                                   : (bf16x8){0, 0, 0, 0, 0, 0, 0, 0};
        *(bf16x8*)&Hl[r * 136 + c8 * 8] = v;
        *(bf16x8*)&Wl[r * 136 + c8 * 8] = *(const bf16x8*)&w2t[r * 128 + c8 * 8];
    }
    __syncthreads();
    int w = t >> 6, lane = t & 63;
    int nn = lane & 15, quad = lane >> 4;
    bf16x8 a[4];
#pragma unroll
    for (int kt = 0; kt < 4; ++kt)
        a[kt] = *(const bf16x8*)&Hl[(w * 16 + nn) * 136 + kt * 32 + quad * 8];
    f32x4 acc[4];
#pragma unroll
    for (int ct = 0; ct < 4; ++ct) {
        acc[ct] = (f32x4){0.f, 0.f, 0.f, 0.f};
#pragma unroll
        for (int kt = 0; kt < 4; ++kt) {
            bf16x8 b = *(const bf16x8*)&Wl[(ct * 16 + nn) * 136 + kt * 32 + quad * 8];
            acc[ct] = __builtin_amdgcn_mfma_f32_16x16x32_bf16(a[kt], b, acc[ct], 0, 0, 0);
        }
    }
#pragma unroll
    for (int r = 0; r < 4; ++r) {
        int row = row0 + w * 16 + quad * 4 + r;
        float dv = (row < N_NODES) ? dinv[row] : 0.f;
#pragma unroll
        for (int ct = 0; ct < 4; ++ct)
            Hl[(w * 16 + quad * 4 + r) * 136 + ct * 16 + nn] = f2bf(acc[ct][r] * dv);
    }
#pragma unroll
    for (int j = 0; j < 4; ++j) {
        int c = lane + j * 64;
        int r = c >> 4, c4 = c & 15;
        int row = row0 + w * 16 + r;
        if (row < N_NODES)
            ((ushort4*)(gsb + (long long)row * 64))[c4] = *(const ushort4*)&Hl[(w * 16 + r) * 136 + c4 * 4];
    }
}

// ---------------- aggregate layer 2: one 8-lane group per node, 8 nodes/wave, 8-deep gather unroll ----------------
__global__ __launch_bounds__(256) void k_agg2(const unsigned short* __restrict__ gsb, const int* __restrict__ rowptr,
                                              const int* __restrict__ csr, const float* __restrict__ dinv,
                                              const float* __restrict__ b2, float* __restrict__ out) {
    unsigned g = (blockIdx.x * 256 + threadIdx.x) >> 3;   // group id == node id
    unsigned li = threadIdx.x & 7;                        // 8 lanes x 16B = full 128B row
    if (g >= N_NODES) return;
    unsigned co = li * 8;
    float a[8];
    {   // self-loop seed
        uint4 sv = *(const uint4*)(gsb + (g << 6) + co);
        a[0] = __uint_as_float(sv.x << 16);
        a[1] = __uint_as_float(sv.x & 0xFFFF0000u);
        a[2] = __uint_as_float(sv.y << 16);
        a[3] = __uint_as_float(sv.y & 0xFFFF0000u);
        a[4] = __uint_as_float(sv.z << 16);
        a[5] = __uint_as_float(sv.z & 0xFFFF0000u);
        a[6] = __uint_as_float(sv.w << 16);
        a[7] = __uint_as_float(sv.w & 0xFFFF0000u);
    }
    int k = rowptr[g], end = rowptr[g + 1];
    for (; k + 7 < end; k += 8) {
        int i0 = csr[k + 0], i1 = csr[k + 1], i2 = csr[k + 2], i3 = csr[k + 3];
        int i4 = csr[k + 4], i5 = csr[k + 5], i6 = csr[k + 6], i7 = csr[k + 7];
        uint4 v0 = *(const uint4*)(gsb + (((unsigned)i0) << 6) + co);
        uint4 v1 = *(const uint4*)(gsb + (((unsigned)i1) << 6) + co);
        uint4 v2 = *(const uint4*)(gsb + (((unsigned)i2) << 6) + co);
        uint4 v3 = *(const uint4*)(gsb + (((unsigned)i3) << 6) + co);
        uint4 v4 = *(const uint4*)(gsb + (((unsigned)i4) << 6) + co);
        uint4 v5 = *(const uint4*)(gsb + (((unsigned)i5) << 6) + co);
        uint4 v6 = *(const uint4*)(gsb + (((unsigned)i6) << 6) + co);
        uint4 v7 = *(const uint4*)(gsb + (((unsigned)i7) << 6) + co);
        acc8(a, v0); acc8(a, v1); acc8(a, v2); acc8(a, v3);
        acc8(a, v4); acc8(a, v5); acc8(a, v6); acc8(a, v7);
    }
    if (k + 3 < end) {
        int i0 = csr[k + 0], i1 = csr[k + 1], i2 = csr[k + 2], i3 = csr[k + 3];
        uint4 v0 = *(const uint4*)(gsb + (((unsigned)i0) << 6) + co);
        uint4 v1 = *(const uint4*)(gsb + (((unsigned)i1) << 6) + co);
        uint4 v2 = *(const uint4*)(gsb + (((unsigned)i2) << 6) + co);
        uint4 v3 = *(const uint4*)(gsb + (((unsigned)i3) << 6) + co);
        acc8(a, v0); acc8(a, v1); acc8(a, v2); acc8(a, v3);
        k += 4;
    }
    for (; k < end; ++k) {
        uint4 v = *(const uint4*)(gsb + (((unsigned)csr[k]) << 6) + co);
        acc8(a, v);
    }
    float dv = dinv[g];
    f32x8 bb = *(const f32x8*)(b2 + li * 8);
    float4 o0 = make_float4(fmaf(dv, a[0], bb[0]), fmaf(dv, a[1], bb[1]),
                            fmaf(dv, a[2], bb[2]), fmaf(dv, a[3], bb[3]));
    float4 o1 = make_float4(fmaf(dv, a[4], bb[4]), fmaf(dv, a[5], bb[5]),
                            fmaf(dv, a[6], bb[6]), fmaf(dv, a[7], bb[7]));
    float* op = out + ((long long)g << 6) + co;
    *(float4*)op = o0;
    *(float4*)(op + 4) = o1;
}

extern "C" void kernel_launch(void* const* d_in, const int* in_sizes, int n_in,
                              void* d_out, int out_size, void* d_ws, size_t ws_size,
                              hipStream_t stream) {
    const float* x  = (const float*)d_in[0];
    const float* W1 = (const float*)d_in[1];
    const float* b1 = (const float*)d_in[2];
    const float* W2 = (const float*)d_in[3];
    const float* b2 = (const float*)d_in[4];
    const int*   ei = (const int*)d_in[5];
    const int* src = ei;
    const int* dst = ei + N_EDGES;
    float* out = (float*)d_out;

    char* ws = (char*)d_ws;
    int*   csr    = (int*)(ws + 0);             // 6.4 MB
    int*   rowptr = (int*)(ws + 6800000);       // 400 KB + 4
    float* dinv   = (float*)(ws + 7200256);     // 400 KB
    int*   bcur   = (int*)(ws + 7604352);       // NB ints
    unsigned short* w1t = (unsigned short*)(ws + 7608448);  // 32 KB bf16 W1^T
    unsigned short* w2t = (unsigned short*)(ws + 7641216);  // 16 KB bf16 W2^T
    int*   ebuf   = (int*)(ws + 8388608);       // 196*10240*4 = 8.03 MB (dead before gemm1)
    unsigned short* hsb = (unsigned short*)(ws + 8388608);  // 25.6 MB bf16 (aliases ebuf)
    unsigned short* h   = (unsigned short*)(ws + 59588608); // 25.6 MB bf16
    unsigned short* gsb = hsb;                   // hsb dead after k_agg1; 12.8 MB bf16

    k_tw<<<97, 256, 0, stream>>>(W1, W2, w1t, w2t, bcur);
    k_bin<<<BIN_BLOCKS, 256, 0, stream>>>(src, dst, bcur, ebuf);
    k_bfill3<<<NB, 256, 0, stream>>>(ebuf, bcur, rowptr, dinv, csr);

    k_gemm1<<<GEMM_BLOCKS, 256, 0, stream>>>(x, w1t, dinv, hsb);
    k_agg1<<<AGG1_BLOCKS, 256, 0, stream>>>(hsb, rowptr, csr, dinv, b1, h);
    k_gemm2<<<GEMM_BLOCKS, 256, 0, stream>>>(h, w2t, dinv, gsb);
    k_agg2<<<AGG2_BLOCKS, 256, 0, stream>>>(gsb, rowptr, csr, dinv, b2, out);
}